// Round 7
// baseline (196.071 us; speedup 1.0000x reference)
//
#include <hip/hip_runtime.h>

// Rank2SymmetricTensorHead — bucket + fully-fused node kernel (wave-pair MLP).
// Algebra (proven absmax 0.0 in rounds 3-6): layernorm is affine per edge =>
//   no[c][u] = invc*( lw_c*(emb[.,c].S1[u] - S2[u]) + lb_c*S3[u] )
// with per-node S1[6][9],S2[6],S3[6]; per-edge mu/var from per-node
// mbar[9]+Gram[45] of emb. Then silu-MLP + W2 -> 9 outputs per node.
//
// Fused kernel, 8 nodes/block (4 waves x 2 nodes):
//   phase0: stats (DPP chains, lane63 -> statsL)        [wave-local]
//   phase1: edges -> S_lds (66 DPP chains, *invc)       [wave-local]
//   phase2: contraction -> noP[pair][c][12]             [block]
//   phase3: MLP — lane owns 2 k's, wave owns node-pair; no-values read as
//           wave-UNIFORM b128 broadcasts (3/step) vs 24 FMA-instr/step
//           => VALU-bound, W1 reads coalesced float2, L1/L2-resident.

#define SQ3  1.73205080756887729f
#define SQ15 3.87298334620741688f
#define SQ5  2.23606797749978970f

#define NB 8   // nodes per fused block

__device__ __forceinline__ float dpp_sum64(float v) {
    // 64-lane sum, result valid in lane 63. Pure VALU.
    int x;
    x = __builtin_amdgcn_update_dpp(0, __float_as_int(v), 0x111, 0xF, 0xF, true); v += __int_as_float(x);
    x = __builtin_amdgcn_update_dpp(0, __float_as_int(v), 0x112, 0xF, 0xF, true); v += __int_as_float(x);
    x = __builtin_amdgcn_update_dpp(0, __float_as_int(v), 0x114, 0xF, 0xF, true); v += __int_as_float(x);
    x = __builtin_amdgcn_update_dpp(0, __float_as_int(v), 0x118, 0xF, 0xF, true); v += __int_as_float(x);
    x = __builtin_amdgcn_update_dpp(0, __float_as_int(v), 0x142, 0xA, 0xF, true); v += __int_as_float(x);
    x = __builtin_amdgcn_update_dpp(0, __float_as_int(v), 0x143, 0xC, 0xF, true); v += __int_as_float(x);
    return v;
}

__device__ __forceinline__ void wave_fence() {
    __builtin_amdgcn_wave_barrier();
    asm volatile("" ::: "memory");
}

__global__ __launch_bounds__(256)
void bucket_kernel(const int* __restrict__ idx1, const int* __restrict__ batch,
                   int* __restrict__ cnt, int* __restrict__ bcnt,
                   int* __restrict__ elist, int slot, int E, int N) {
    const int i  = blockIdx.x * 256 + threadIdx.x;
    const int i4 = i * 4;
    if (i4 + 3 < E) {
        const int4 v = *(const int4*)&idx1[i4];
        int p;
        p = atomicAdd(&cnt[v.x], 1); if (p < slot) elist[(size_t)v.x * slot + p] = i4;
        p = atomicAdd(&cnt[v.y], 1); if (p < slot) elist[(size_t)v.y * slot + p] = i4 + 1;
        p = atomicAdd(&cnt[v.z], 1); if (p < slot) elist[(size_t)v.z * slot + p] = i4 + 2;
        p = atomicAdd(&cnt[v.w], 1); if (p < slot) elist[(size_t)v.w * slot + p] = i4 + 3;
    } else {
        for (int k2 = i4; k2 < E; ++k2) {
            const int nn = idx1[k2];
            const int p = atomicAdd(&cnt[nn], 1);
            if (p < slot) elist[(size_t)nn * slot + p] = k2;
        }
    }
    if (i < N) atomicAdd(&bcnt[batch[i]], 1);
}

__global__ __launch_bounds__(256)
void fused_kernel(const float* __restrict__ emb, const float* __restrict__ vec,
                  const int* __restrict__ cnt, const int* __restrict__ elist, int slot,
                  const float* __restrict__ sph_w,
                  const float* __restrict__ ln_w, const float* __restrict__ ln_b,
                  const float* __restrict__ W1, const float* __restrict__ b1,
                  const float* __restrict__ W2, const float* __restrict__ b2,
                  const int* __restrict__ batch, const int* __restrict__ bcnt,
                  float* __restrict__ out, int N)
{
    __shared__ float statsL[4][2][56];   // [wave][node-in-pair]: mbar[9], Gram[45]
    __shared__ float S_lds[4][2][68];    // S1[54],S2[6],S3[6], invc-scaled
    __shared__ float noP[4][128][12];    // [pair][c][n0:u0..5, n1:u0..5]

    const int t = threadIdx.x;
    const int lane = t & 63, wv = t >> 6;
    const int nb = blockIdx.x * NB;

    // ================= phase 0: per-node stats (wave-local) =================
    #pragma unroll
    for (int q = 0; q < 2; ++q) {
        const int n = nb + wv * 2 + q;
        if (n >= N) break;
        const float* eb = emb + (size_t)n * 1152;
        float er0[9], er1[9];
        #pragma unroll
        for (int l = 0; l < 9; ++l) { er0[l] = eb[l * 128 + lane]; er1[l] = eb[l * 128 + 64 + lane]; }
        #pragma unroll
        for (int l = 0; l < 9; ++l) {
            const float tot = dpp_sum64(er0[l] + er1[l]);
            if (lane == 63) statsL[wv][q][l] = tot;
        }
        int idx = 9;
        #pragma unroll
        for (int l = 0; l < 9; ++l) {
            #pragma unroll
            for (int l2 = l; l2 < 9; ++l2) {
                const float tot = dpp_sum64(er0[l] * er0[l2] + er1[l] * er1[l2]);
                if (lane == 63) statsL[wv][q][idx] = tot;
                ++idx;
            }
        }
    }
    wave_fence();

    // ================= phase 1: edges -> S_lds (wave-local) =================
    const float spw0 = sph_w[0], spw1 = sph_w[1], spw2 = sph_w[2];
    #pragma unroll
    for (int q = 0; q < 2; ++q) {
        const int n = nb + wv * 2 + q;
        if (n >= N) break;
        const int   cntn = cnt[n];
        const int   cnE  = min(cntn, slot);
        const float invc = 1.f / (float)(cntn > 0 ? cntn : 1);
        const float inv128 = 1.f / 128.f;
        const float* st = &statsL[wv][q][0];

        float t1[9], mru = 0.f, op[6];
        #pragma unroll
        for (int l = 0; l < 9; ++l) t1[l] = 0.f;
        #pragma unroll
        for (int u = 0; u < 6; ++u) op[u] = 0.f;

        if (lane < cnE) {
            const int e = elist[(size_t)n * slot + lane];
            const float vx = vec[e * 3 + 0];
            const float vy = vec[e * 3 + 1];
            const float vz = vec[e * 3 + 2];
            const float rr = vx * vx + vy * vy + vz * vz;

            const float a1x = SQ3 * vx, a1y = SQ3 * vy, a1z = SQ3 * vz;
            const float q0 = SQ15 * vx * vy;
            const float q1 = SQ15 * vy * vz;
            const float q2 = 0.5f * SQ5 * (3.f * vz * vz - rr);
            const float q3 = SQ15 * vx * vz;
            const float q4 = 0.5f * SQ15 * (vx * vx - vy * vy);
            const float inv1 = spw1 * rsqrtf((a1x*a1x + a1y*a1y + a1z*a1z) * (1.f/3.f) + 1e-6f);
            const float inv2 = spw2 * rsqrtf((q0*q0 + q1*q1 + q2*q2 + q3*q3 + q4*q4) * (1.f/5.f) + 1e-6f);

            float sh[9];
            sh[0] = spw0 * rsqrtf(1.0f + 1e-6f);
            sh[1] = a1x * inv1; sh[2] = a1y * inv1; sh[3] = a1z * inv1;
            sh[4] = q0 * inv2;  sh[5] = q1 * inv2;  sh[6] = q2 * inv2;
            sh[7] = q3 * inv2;  sh[8] = q4 * inv2;

            float mu = 0.f;
            #pragma unroll
            for (int l = 0; l < 9; ++l) mu += sh[l] * st[l];
            mu *= inv128;

            float x2 = 0.f;
            {
                int idx = 9;
                #pragma unroll
                for (int l = 0; l < 9; ++l) {
                    x2 += st[idx] * sh[l] * sh[l]; ++idx;
                    #pragma unroll
                    for (int l2 = l + 1; l2 < 9; ++l2) {
                        x2 += st[idx] * (2.f * sh[l] * sh[l2]); ++idx;
                    }
                }
            }
            x2 *= inv128;

            const float rinv = rsqrtf(x2 - mu * mu + 1e-5f);
            #pragma unroll
            for (int l = 0; l < 9; ++l) t1[l] = rinv * sh[l];
            mru = rinv * mu;
            op[0] = vx*vx; op[1] = vx*vy; op[2] = vx*vz;
            op[3] = vy*vy; op[4] = vy*vz; op[5] = vz*vz;
        }

        #pragma unroll
        for (int u = 0; u < 6; ++u) {
            #pragma unroll
            for (int l = 0; l < 9; ++l) {
                const float tot = dpp_sum64(op[u] * t1[l]);
                if (lane == 63) S_lds[wv][q][u * 9 + l] = tot * invc;
            }
        }
        #pragma unroll
        for (int u = 0; u < 6; ++u) {
            const float tot = dpp_sum64(op[u] * mru);
            if (lane == 63) S_lds[wv][q][54 + u] = tot * invc;
        }
        #pragma unroll
        for (int u = 0; u < 6; ++u) {
            const float tot = dpp_sum64(op[u]);
            if (lane == 63) S_lds[wv][q][60 + u] = tot * invc;
        }
    }
    __syncthreads();

    // ================= phase 2: contraction -> noP =================
    {
        const int c = t & 127, hf = t >> 7;
        const float lwc = ln_w[c], lbc = ln_b[c];
        #pragma unroll
        for (int j = 0; j < 4; ++j) {
            const int nid = hf * 4 + j;
            const int n = nb + nid;
            if (n >= N) break;
            const float* eb = emb + (size_t)n * 1152 + c;
            float e[9];
            #pragma unroll
            for (int l = 0; l < 9; ++l) e[l] = eb[l * 128];
            const float* Sp = &S_lds[nid >> 1][nid & 1][0];
            float val[6];
            #pragma unroll
            for (int u = 0; u < 6; ++u) {
                float a = 0.f;
                #pragma unroll
                for (int l = 0; l < 9; ++l) a += e[l] * Sp[u * 9 + l];
                val[u] = lwc * (a - Sp[54 + u]) + lbc * Sp[60 + u];
            }
            float* wp = &noP[nid >> 1][c][(nid & 1) * 6];
            *(float2*)(wp + 0) = make_float2(val[0], val[1]);
            *(float2*)(wp + 2) = make_float2(val[2], val[3]);
            *(float2*)(wp + 4) = make_float2(val[4], val[5]);
        }
    }
    __syncthreads();

    // ================= phase 3: MLP — wave owns node pair, lane owns 2 k's ==
    {
        const int n0 = nb + wv * 2;
        const int n1 = n0 + 1;
        const int k2 = 2 * lane;

        float2 acc[2][6];
        #pragma unroll
        for (int p = 0; p < 2; ++p)
            #pragma unroll
            for (int u = 0; u < 6; ++u) { acc[p][u].x = 0.f; acc[p][u].y = 0.f; }

        const float* w1p = W1 + k2;
        #pragma unroll 4
        for (int c = 0; c < 128; ++c) {
            const float2 w = *(const float2*)(w1p + (size_t)c * 128);
            const float4 nA = *(const float4*)&noP[wv][c][0];   // n0 u0..3
            const float4 nB = *(const float4*)&noP[wv][c][4];   // n0 u4,5 | n1 u0,1
            const float4 nC = *(const float4*)&noP[wv][c][8];   // n1 u2..5
            acc[0][0].x = fmaf(nA.x, w.x, acc[0][0].x); acc[0][0].y = fmaf(nA.x, w.y, acc[0][0].y);
            acc[0][1].x = fmaf(nA.y, w.x, acc[0][1].x); acc[0][1].y = fmaf(nA.y, w.y, acc[0][1].y);
            acc[0][2].x = fmaf(nA.z, w.x, acc[0][2].x); acc[0][2].y = fmaf(nA.z, w.y, acc[0][2].y);
            acc[0][3].x = fmaf(nA.w, w.x, acc[0][3].x); acc[0][3].y = fmaf(nA.w, w.y, acc[0][3].y);
            acc[0][4].x = fmaf(nB.x, w.x, acc[0][4].x); acc[0][4].y = fmaf(nB.x, w.y, acc[0][4].y);
            acc[0][5].x = fmaf(nB.y, w.x, acc[0][5].x); acc[0][5].y = fmaf(nB.y, w.y, acc[0][5].y);
            acc[1][0].x = fmaf(nB.z, w.x, acc[1][0].x); acc[1][0].y = fmaf(nB.z, w.y, acc[1][0].y);
            acc[1][1].x = fmaf(nB.w, w.x, acc[1][1].x); acc[1][1].y = fmaf(nB.w, w.y, acc[1][1].y);
            acc[1][2].x = fmaf(nC.x, w.x, acc[1][2].x); acc[1][2].y = fmaf(nC.x, w.y, acc[1][2].y);
            acc[1][3].x = fmaf(nC.y, w.x, acc[1][3].x); acc[1][3].y = fmaf(nC.y, w.y, acc[1][3].y);
            acc[1][4].x = fmaf(nC.z, w.x, acc[1][4].x); acc[1][4].y = fmaf(nC.z, w.y, acc[1][4].y);
            acc[1][5].x = fmaf(nC.w, w.x, acc[1][5].x); acc[1][5].y = fmaf(nC.w, w.y, acc[1][5].y);
        }

        const float2 b1v = *(const float2*)&b1[k2];
        const float2 w2v = *(const float2*)&W2[k2];
        float sv[2][6];
        #pragma unroll
        for (int p = 0; p < 2; ++p) {
            #pragma unroll
            for (int u = 0; u < 6; ++u) {
                const float zx = acc[p][u].x + b1v.x;
                const float zy = acc[p][u].y + b1v.y;
                const float gx = zx / (1.f + __expf(-zx));
                const float gy = zy / (1.f + __expf(-zy));
                sv[p][u] = dpp_sum64(fmaf(gx, w2v.x, gy * w2v.y));
            }
        }

        if (lane == 63) {
            const float bb2 = b2[0];
            #pragma unroll
            for (int p = 0; p < 2; ++p) {
                const int n = (p == 0) ? n0 : n1;
                if (n < N) {
                    const int bidx = batch[n];
                    const int cb = bcnt[bidx];
                    const float ic = 1.f / (float)(cb > 0 ? cb : 1);
                    const int base = bidx * 9;
                    const float v0 = (sv[p][0] + bb2) * ic;
                    const float v1 = (sv[p][1] + bb2) * ic;
                    const float v2 = (sv[p][2] + bb2) * ic;
                    const float v3 = (sv[p][3] + bb2) * ic;
                    const float v4 = (sv[p][4] + bb2) * ic;
                    const float v5 = (sv[p][5] + bb2) * ic;
                    atomicAdd(&out[base + 0], v0);
                    atomicAdd(&out[base + 1], v1);
                    atomicAdd(&out[base + 2], v2);
                    atomicAdd(&out[base + 3], v1);
                    atomicAdd(&out[base + 4], v3);
                    atomicAdd(&out[base + 5], v4);
                    atomicAdd(&out[base + 6], v2);
                    atomicAdd(&out[base + 7], v4);
                    atomicAdd(&out[base + 8], v5);
                }
            }
        }
    }
}

extern "C" void kernel_launch(void* const* d_in, const int* in_sizes, int n_in,
                              void* d_out, int out_size, void* d_ws, size_t ws_size,
                              hipStream_t stream) {
    const float* emb   = (const float*)d_in[0];
    const float* vec   = (const float*)d_in[1];
    const int*   eidx  = (const int*)  d_in[2];
    const int*   batch = (const int*)  d_in[3];
    const float* sph_w = (const float*)d_in[4];
    const float* ln_w  = (const float*)d_in[5];
    const float* ln_b  = (const float*)d_in[6];
    const float* W1    = (const float*)d_in[7];
    const float* b1    = (const float*)d_in[8];
    const float* W2    = (const float*)d_in[9];
    const float* b2    = (const float*)d_in[10];

    const int N = in_sizes[3];
    const int E = in_sizes[1] / 3;
    const int B = out_size / 9;
    const int* idx1 = eidx + E;   // edge_index[1]

    // ws: [cnt N][bcnt B][elist N*slot]
    int slot = 64;
    {
        const size_t base = (size_t)(N + B);
        while (slot > 1 && (base + (size_t)N * slot) * 4 > ws_size) slot >>= 1;
    }
    int* cnt   = (int*)d_ws;
    int* bcnt  = cnt + N;
    int* elist = bcnt + B;

    hipMemsetAsync(d_out, 0, (size_t)out_size * sizeof(float), stream);
    hipMemsetAsync(cnt, 0, (size_t)(N + B) * sizeof(int), stream);

    const int pwork = max((E + 3) / 4, N);
    bucket_kernel<<<(pwork + 255) / 256, 256, 0, stream>>>(idx1, batch, cnt, bcnt,
                                                           elist, slot, E, N);
    fused_kernel<<<(N + NB - 1) / NB, 256, 0, stream>>>(
        emb, vec, cnt, elist, slot, sph_w, ln_w, ln_b,
        W1, b1, W2, b2, batch, bcnt, (float*)d_out, N);
}

// Round 8
// 188.294 us; speedup vs baseline: 1.0413x; 1.0413x over previous
//
#include <hip/hip_runtime.h>

// Rank2SymmetricTensorHead — bucket + fused kernel, wave-per-node, barrier-free.
// Algebra (absmax 0.0 since round 3): layernorm is affine per edge =>
//   no[c][u] = invc*( lw_c*(emb[.,c].S1[u] - S2[u]) + lb_c*S3[u] )
// per-node S1[6][9],S2[6],S3[6]; per-edge mu/var from per-node mbar[9]+Gram[45].
// Every wave owns ONE node end-to-end; all LDS is per-wave => no __syncthreads,
// only wave_barrier fences. 4 waves/block, 2048 blocks, LDS 18 KB, VGPR-lean.

#define SQ3  1.73205080756887729f
#define SQ15 3.87298334620741688f
#define SQ5  2.23606797749978970f

__device__ __forceinline__ float dpp_sum64(float v) {
    // 64-lane sum, result valid in lane 63. Pure VALU.
    int x;
    x = __builtin_amdgcn_update_dpp(0, __float_as_int(v), 0x111, 0xF, 0xF, true); v += __int_as_float(x);
    x = __builtin_amdgcn_update_dpp(0, __float_as_int(v), 0x112, 0xF, 0xF, true); v += __int_as_float(x);
    x = __builtin_amdgcn_update_dpp(0, __float_as_int(v), 0x114, 0xF, 0xF, true); v += __int_as_float(x);
    x = __builtin_amdgcn_update_dpp(0, __float_as_int(v), 0x118, 0xF, 0xF, true); v += __int_as_float(x);
    x = __builtin_amdgcn_update_dpp(0, __float_as_int(v), 0x142, 0xA, 0xF, true); v += __int_as_float(x);
    x = __builtin_amdgcn_update_dpp(0, __float_as_int(v), 0x143, 0xC, 0xF, true); v += __int_as_float(x);
    return v;
}

__device__ __forceinline__ void wave_fence() {
    __builtin_amdgcn_wave_barrier();
    asm volatile("" ::: "memory");
}

__global__ __launch_bounds__(256)
void bucket_kernel(const int* __restrict__ idx1, const int* __restrict__ batch,
                   int* __restrict__ cnt, int* __restrict__ bcnt,
                   int* __restrict__ elist, int slot, int E, int N) {
    const int i  = blockIdx.x * 256 + threadIdx.x;
    const int i4 = i * 4;
    if (i4 + 3 < E) {
        const int4 v = *(const int4*)&idx1[i4];
        int p;
        p = atomicAdd(&cnt[v.x], 1); if (p < slot) elist[(size_t)v.x * slot + p] = i4;
        p = atomicAdd(&cnt[v.y], 1); if (p < slot) elist[(size_t)v.y * slot + p] = i4 + 1;
        p = atomicAdd(&cnt[v.z], 1); if (p < slot) elist[(size_t)v.z * slot + p] = i4 + 2;
        p = atomicAdd(&cnt[v.w], 1); if (p < slot) elist[(size_t)v.w * slot + p] = i4 + 3;
    } else {
        for (int k2 = i4; k2 < E; ++k2) {
            const int nn = idx1[k2];
            const int p = atomicAdd(&cnt[nn], 1);
            if (p < slot) elist[(size_t)nn * slot + p] = k2;
        }
    }
    if (i < N) atomicAdd(&bcnt[batch[i]], 1);
}

__global__ __launch_bounds__(256)
void fused_kernel(const float* __restrict__ emb, const float* __restrict__ vec,
                  const int* __restrict__ cnt, const int* __restrict__ elist, int slot,
                  const float* __restrict__ sph_w,
                  const float* __restrict__ ln_w, const float* __restrict__ ln_b,
                  const float* __restrict__ W1, const float* __restrict__ b1,
                  const float* __restrict__ W2, const float* __restrict__ b2,
                  const int* __restrict__ batch, const int* __restrict__ bcnt,
                  float* __restrict__ out, int N)
{
    __shared__ float statsL[4][56];      // per-wave: mbar[9], Gram[45]
    __shared__ float S_lds[4][68];       // per-wave: S1[54],S2[6],S3[6] (invc-scaled)
    __shared__ float noP[4][128][8];     // per-wave: no[c][u0..5], pad to 8

    const int lane = threadIdx.x & 63;
    const int wv   = threadIdx.x >> 6;
    const int n    = blockIdx.x * 4 + wv;
    if (n >= N) return;

    const float* eb = emb + (size_t)n * 1152;

    // ================= phase 0: per-node stats (emb read #1, er regs die here)
    {
        float er0[9], er1[9];
        #pragma unroll
        for (int l = 0; l < 9; ++l) { er0[l] = eb[l * 128 + lane]; er1[l] = eb[l * 128 + 64 + lane]; }
        #pragma unroll
        for (int l = 0; l < 9; ++l) {
            const float tot = dpp_sum64(er0[l] + er1[l]);
            if (lane == 63) statsL[wv][l] = tot;
        }
        int idx = 9;
        #pragma unroll
        for (int l = 0; l < 9; ++l) {
            #pragma unroll
            for (int l2 = l; l2 < 9; ++l2) {
                const float tot = dpp_sum64(er0[l] * er0[l2] + er1[l] * er1[l2]);
                if (lane == 63) statsL[wv][idx] = tot;
                ++idx;
            }
        }
    }
    wave_fence();

    // ================= phase 1: edges -> S_lds (wave-local) =================
    const int   cntn = cnt[n];
    {
        const int   cnE  = min(cntn, slot);
        const float invc = 1.f / (float)(cntn > 0 ? cntn : 1);
        const float inv128 = 1.f / 128.f;
        const float* st = &statsL[wv][0];

        float t1[9], mru = 0.f, op[6];
        #pragma unroll
        for (int l = 0; l < 9; ++l) t1[l] = 0.f;
        #pragma unroll
        for (int u = 0; u < 6; ++u) op[u] = 0.f;

        if (lane < cnE) {
            const int e = elist[(size_t)n * slot + lane];
            const float vx = vec[e * 3 + 0];
            const float vy = vec[e * 3 + 1];
            const float vz = vec[e * 3 + 2];
            const float rr = vx * vx + vy * vy + vz * vz;

            const float a1x = SQ3 * vx, a1y = SQ3 * vy, a1z = SQ3 * vz;
            const float q0 = SQ15 * vx * vy;
            const float q1 = SQ15 * vy * vz;
            const float q2 = 0.5f * SQ5 * (3.f * vz * vz - rr);
            const float q3 = SQ15 * vx * vz;
            const float q4 = 0.5f * SQ15 * (vx * vx - vy * vy);
            const float inv1 = sph_w[1] * rsqrtf((a1x*a1x + a1y*a1y + a1z*a1z) * (1.f/3.f) + 1e-6f);
            const float inv2 = sph_w[2] * rsqrtf((q0*q0 + q1*q1 + q2*q2 + q3*q3 + q4*q4) * (1.f/5.f) + 1e-6f);

            float sh[9];
            sh[0] = sph_w[0] * rsqrtf(1.0f + 1e-6f);
            sh[1] = a1x * inv1; sh[2] = a1y * inv1; sh[3] = a1z * inv1;
            sh[4] = q0 * inv2;  sh[5] = q1 * inv2;  sh[6] = q2 * inv2;
            sh[7] = q3 * inv2;  sh[8] = q4 * inv2;

            float mu = 0.f;
            #pragma unroll
            for (int l = 0; l < 9; ++l) mu += sh[l] * st[l];
            mu *= inv128;

            float x2 = 0.f;
            {
                int idx = 9;
                #pragma unroll
                for (int l = 0; l < 9; ++l) {
                    x2 += st[idx] * sh[l] * sh[l]; ++idx;
                    #pragma unroll
                    for (int l2 = l + 1; l2 < 9; ++l2) {
                        x2 += st[idx] * (2.f * sh[l] * sh[l2]); ++idx;
                    }
                }
            }
            x2 *= inv128;

            const float rinv = rsqrtf(x2 - mu * mu + 1e-5f);
            #pragma unroll
            for (int l = 0; l < 9; ++l) t1[l] = rinv * sh[l];
            mru = rinv * mu;
            op[0] = vx*vx; op[1] = vx*vy; op[2] = vx*vz;
            op[3] = vy*vy; op[4] = vy*vz; op[5] = vz*vz;
        }

        #pragma unroll
        for (int u = 0; u < 6; ++u) {
            #pragma unroll
            for (int l = 0; l < 9; ++l) {
                const float tot = dpp_sum64(op[u] * t1[l]);
                if (lane == 63) S_lds[wv][u * 9 + l] = tot * invc;
            }
        }
        #pragma unroll
        for (int u = 0; u < 6; ++u) {
            const float tot = dpp_sum64(op[u] * mru);
            if (lane == 63) S_lds[wv][54 + u] = tot * invc;
        }
        #pragma unroll
        for (int u = 0; u < 6; ++u) {
            const float tot = dpp_sum64(op[u]);
            if (lane == 63) S_lds[wv][60 + u] = tot * invc;
        }
    }
    wave_fence();

    // ================= phase 2: contraction (emb read #2, L2-warm) ==========
    {
        const int c0 = lane, c1 = lane + 64;
        const float lw0 = ln_w[c0], lb0 = ln_b[c0];
        const float lw1 = ln_w[c1], lb1 = ln_b[c1];
        float er0[9], er1[9];
        #pragma unroll
        for (int l = 0; l < 9; ++l) { er0[l] = eb[l * 128 + c0]; er1[l] = eb[l * 128 + c1]; }
        const float* Sp = &S_lds[wv][0];
        float v0[6], v1[6];
        #pragma unroll
        for (int u = 0; u < 6; ++u) {
            float a0 = 0.f, a1 = 0.f;
            #pragma unroll
            for (int l = 0; l < 9; ++l) {
                const float s = Sp[u * 9 + l];
                a0 = fmaf(er0[l], s, a0);
                a1 = fmaf(er1[l], s, a1);
            }
            const float S2u = Sp[54 + u], S3u = Sp[60 + u];
            v0[u] = fmaf(lw0, a0 - S2u, lb0 * S3u);
            v1[u] = fmaf(lw1, a1 - S2u, lb1 * S3u);
        }
        float* p0 = &noP[wv][c0][0];
        *(float4*)(p0)     = make_float4(v0[0], v0[1], v0[2], v0[3]);
        *(float2*)(p0 + 4) = make_float2(v0[4], v0[5]);
        float* p1 = &noP[wv][c1][0];
        *(float4*)(p1)     = make_float4(v1[0], v1[1], v1[2], v1[3]);
        *(float2*)(p1 + 4) = make_float2(v1[4], v1[5]);
    }
    wave_fence();

    // ================= phase 3: MLP — lane owns 2 k's, uniform noP broadcasts
    {
        const int k2 = 2 * lane;
        float2 acc[6];
        #pragma unroll
        for (int u = 0; u < 6; ++u) { acc[u].x = 0.f; acc[u].y = 0.f; }

        const float* w1p = W1 + k2;
        #pragma unroll 8
        for (int c = 0; c < 128; ++c) {
            const float2 w  = *(const float2*)(w1p + (size_t)c * 128);
            const float4 nA = *(const float4*)&noP[wv][c][0];   // u0..3 (uniform)
            const float2 nB = *(const float2*)&noP[wv][c][4];   // u4,5  (uniform)
            acc[0].x = fmaf(nA.x, w.x, acc[0].x); acc[0].y = fmaf(nA.x, w.y, acc[0].y);
            acc[1].x = fmaf(nA.y, w.x, acc[1].x); acc[1].y = fmaf(nA.y, w.y, acc[1].y);
            acc[2].x = fmaf(nA.z, w.x, acc[2].x); acc[2].y = fmaf(nA.z, w.y, acc[2].y);
            acc[3].x = fmaf(nA.w, w.x, acc[3].x); acc[3].y = fmaf(nA.w, w.y, acc[3].y);
            acc[4].x = fmaf(nB.x, w.x, acc[4].x); acc[4].y = fmaf(nB.x, w.y, acc[4].y);
            acc[5].x = fmaf(nB.y, w.x, acc[5].x); acc[5].y = fmaf(nB.y, w.y, acc[5].y);
        }

        const float2 b1v = *(const float2*)&b1[k2];
        const float2 w2v = *(const float2*)&W2[k2];
        float sv[6];
        #pragma unroll
        for (int u = 0; u < 6; ++u) {
            const float zx = acc[u].x + b1v.x;
            const float zy = acc[u].y + b1v.y;
            const float gx = zx / (1.f + __expf(-zx));
            const float gy = zy / (1.f + __expf(-zy));
            sv[u] = dpp_sum64(fmaf(gx, w2v.x, gy * w2v.y));
        }

        if (lane == 63) {
            const float bb2 = b2[0];
            const int bidx = batch[n];
            const int cb = bcnt[bidx];
            const float ic = 1.f / (float)(cb > 0 ? cb : 1);
            const int base = bidx * 9;
            const float o0 = (sv[0] + bb2) * ic;
            const float o1 = (sv[1] + bb2) * ic;
            const float o2 = (sv[2] + bb2) * ic;
            const float o3 = (sv[3] + bb2) * ic;
            const float o4 = (sv[4] + bb2) * ic;
            const float o5 = (sv[5] + bb2) * ic;
            atomicAdd(&out[base + 0], o0);
            atomicAdd(&out[base + 1], o1);
            atomicAdd(&out[base + 2], o2);
            atomicAdd(&out[base + 3], o1);
            atomicAdd(&out[base + 4], o3);
            atomicAdd(&out[base + 5], o4);
            atomicAdd(&out[base + 6], o2);
            atomicAdd(&out[base + 7], o4);
            atomicAdd(&out[base + 8], o5);
        }
    }
}

extern "C" void kernel_launch(void* const* d_in, const int* in_sizes, int n_in,
                              void* d_out, int out_size, void* d_ws, size_t ws_size,
                              hipStream_t stream) {
    const float* emb   = (const float*)d_in[0];
    const float* vec   = (const float*)d_in[1];
    const int*   eidx  = (const int*)  d_in[2];
    const int*   batch = (const int*)  d_in[3];
    const float* sph_w = (const float*)d_in[4];
    const float* ln_w  = (const float*)d_in[5];
    const float* ln_b  = (const float*)d_in[6];
    const float* W1    = (const float*)d_in[7];
    const float* b1    = (const float*)d_in[8];
    const float* W2    = (const float*)d_in[9];
    const float* b2    = (const float*)d_in[10];

    const int N = in_sizes[3];
    const int E = in_sizes[1] / 3;
    const int B = out_size / 9;
    const int* idx1 = eidx + E;   // edge_index[1]

    // ws: [cnt N][bcnt B][elist N*slot]
    int slot = 64;
    {
        const size_t base = (size_t)(N + B);
        while (slot > 1 && (base + (size_t)N * slot) * 4 > ws_size) slot >>= 1;
    }
    int* cnt   = (int*)d_ws;
    int* bcnt  = cnt + N;
    int* elist = bcnt + B;

    hipMemsetAsync(d_out, 0, (size_t)out_size * sizeof(float), stream);
    hipMemsetAsync(cnt, 0, (size_t)(N + B) * sizeof(int), stream);

    const int pwork = max((E + 3) / 4, N);
    bucket_kernel<<<(pwork + 255) / 256, 256, 0, stream>>>(idx1, batch, cnt, bcnt,
                                                           elist, slot, E, N);
    fused_kernel<<<(N + 3) / 4, 256, 0, stream>>>(
        emb, vec, cnt, elist, slot, sph_w, ln_w, ln_b,
        W1, b1, W2, b2, batch, bcnt, (float*)d_out, N);
}